// Round 8
// baseline (356.815 us; speedup 1.0000x reference)
//
#include <hip/hip_runtime.h>

typedef _Float16 half8_t __attribute__((ext_vector_type(8)));
typedef _Float16 half4_t __attribute__((ext_vector_type(4)));
typedef float    float4_t __attribute__((ext_vector_type(4)));

#define OMEGA_C 30.0f
#define LDKA 40
#define LDKB 36

#define BARRIER() do {                                        \
    asm volatile("s_waitcnt lgkmcnt(0)" ::: "memory");        \
    __builtin_amdgcn_s_barrier();                             \
    asm volatile("" ::: "memory");                            \
  } while (0)

// ---------------- shared per-kernel boilerplate ----------------
#define SETUP_COMMON()                                                          \
  const int tid = threadIdx.x;                                                  \
  const int b  = blockIdx.x;                                                    \
  const int u  = (b & 7) * 1024 + (b >> 3);                                     \
  const int tile = u >> 3;                                                      \
  const int mh   = (u >> 2) & 1;                                                \
  const int nq   = u & 3;                                                       \
  const int hiw   = ((const int*)idx_raw)[2 * (tid & 63) + 1];                  \
  const bool is32 = __any(hiw != 0);                                            \
  const int ch = is32 ? ((const int*)idx_raw)[tile]                             \
                      : (int)(((const long long*)idx_raw)[tile]);               \
  const int a_row = tid >> 3;                                                   \
  const int a_col = (tid & 7) * 4;                                              \
  const int b_kq = tid >> 6;                                                    \
  const int b_n  = tid & 63;

#define ISSUE_A(s)                                                              \
  do {                                                                          \
    const int k0_ = (s) * 32;                                                   \
    _Pragma("unroll")                                                           \
    for (int p_ = 0; p_ < 4; ++p_)                                              \
      xr[p_] = *(const float4_t*)(Xg + (size_t)(a_row + 32 * p_) * 256 + k0_ + a_col); \
  } while (0)

#define ISSUE_B(s)                                                              \
  do {                                                                          \
    const int k0_ = (s) * 32;                                                   \
    _Pragma("unroll")                                                           \
    for (int j_ = 0; j_ < 4; ++j_) {                                            \
      wb[j_]     = Wg[(size_t)(k0_ + b_kq * 4 + j_) * 256 + b_n];               \
      wb[j_ + 4] = Wg[(size_t)(k0_ + 16 + b_kq * 4 + j_) * 256 + b_n];          \
    }                                                                           \
  } while (0)

#define STORE_AB(buf)                                                           \
  do {                                                                          \
    _Pragma("unroll")                                                           \
    for (int p_ = 0; p_ < 4; ++p_) {                                            \
      half4_t h_ = {(_Float16)xr[p_].x, (_Float16)xr[p_].y,                     \
                    (_Float16)xr[p_].z, (_Float16)xr[p_].w};                    \
      *(half4_t*)&Al[buf][a_row + 32 * p_][a_col] = h_;                         \
    }                                                                           \
    half4_t hb0_ = {(_Float16)wb[0], (_Float16)wb[1],                           \
                    (_Float16)wb[2], (_Float16)wb[3]};                          \
    half4_t hb1_ = {(_Float16)wb[4], (_Float16)wb[5],                           \
                    (_Float16)wb[6], (_Float16)wb[7]};                          \
    *(half4_t*)&Bl[buf][b_n][b_kq * 4]      = hb0_;                             \
    *(half4_t*)&Bl[buf][b_n][16 + b_kq * 4] = hb1_;                             \
  } while (0)

// ================= A: full kernel (R7 verbatim, writes d_out) =================
__global__ __launch_bounds__(256, 4)
void siren_tile_gemm(const float* __restrict__ x,
                     const float* __restrict__ w,
                     const float* __restrict__ bias,
                     const void* __restrict__ idx_raw,
                     float* __restrict__ out) {
  __shared__ __align__(16) _Float16 Al[2][128][LDKA];
  __shared__ __align__(16) _Float16 Bl[2][64][LDKB];
  SETUP_COMMON();

  const float* __restrict__ Xg = x + (size_t)tile * 65536 + (size_t)mh * 128 * 256;
  const float* __restrict__ Wg = w + (size_t)ch * 65536 + nq * 64;
  float*       __restrict__ Og = out + (size_t)tile * 65536 + (size_t)mh * 128 * 256 + nq * 64;

  float4_t acc[4][2];
#pragma unroll
  for (int m = 0; m < 4; ++m)
#pragma unroll
    for (int n = 0; n < 2; ++n)
      acc[m][n] = (float4_t){0.f, 0.f, 0.f, 0.f};

  float4_t xr[4];
  float    wb[8];

  ISSUE_A(0); ISSUE_B(0); STORE_AB(0); BARRIER();

  const int lane = tid & 63;
  const int wid  = tid >> 6;
  const int wm   = (wid >> 1) * 64;
  const int wn   = (wid & 1) * 32;
  const int fr   = lane & 15;
  const int kg   = lane >> 4;

#pragma unroll 2
  for (int s = 0; s < 8; ++s) {
    const int cur = s & 1;
    if (s + 1 < 8) { ISSUE_A(s + 1); ISSUE_B(s + 1); }

    half8_t af[4], bf[2];
#pragma unroll
    for (int m = 0; m < 4; ++m)
      af[m] = *(const half8_t*)&Al[cur][wm + m * 16 + fr][kg * 8];
#pragma unroll
    for (int n = 0; n < 2; ++n) {
      const int r = wn + n * 16 + fr;
      half4_t lo = *(const half4_t*)&Bl[cur][r][kg * 8];
      half4_t hi = *(const half4_t*)&Bl[cur][r][kg * 8 + 4];
      bf[n] = (half8_t){lo.x, lo.y, lo.z, lo.w, hi.x, hi.y, hi.z, hi.w};
    }

#pragma unroll
    for (int m = 0; m < 4; ++m)
#pragma unroll
      for (int n = 0; n < 2; ++n)
        acc[m][n] = __builtin_amdgcn_mfma_f32_16x16x32_f16(af[m], bf[n], acc[m][n], 0, 0, 0);

    if (s + 1 < 8) { STORE_AB(cur ^ 1); BARRIER(); }
  }

  float bv[2];
#pragma unroll
  for (int n = 0; n < 2; ++n) bv[n] = OMEGA_C * bias[nq * 64 + wn + n * 16 + fr];

#pragma unroll
  for (int m = 0; m < 4; ++m)
#pragma unroll
    for (int n = 0; n < 2; ++n)
#pragma unroll
      for (int j = 0; j < 4; ++j) {
        const int row = wm + m * 16 + kg * 4 + j;
        const int col = wn + n * 16 + fr;
        Og[(size_t)row * 256 + col] = __sinf(fmaf(OMEGA_C, acc[m][n][j], bv[n]));
      }
}

// ========== B: staging-only ablation (real loads+cvt+ds_write+barriers) ==========
__global__ __launch_bounds__(256, 4)
void siren_ablate_stage(const float* __restrict__ x,
                        const float* __restrict__ w,
                        const void* __restrict__ idx_raw,
                        float* __restrict__ sink) {
  __shared__ __align__(16) _Float16 Al[2][128][LDKA];
  __shared__ __align__(16) _Float16 Bl[2][64][LDKB];
  SETUP_COMMON();
  (void)mh;

  const float* __restrict__ Xg = x + (size_t)tile * 65536 + (size_t)mh * 128 * 256;
  const float* __restrict__ Wg = w + (size_t)ch * 65536 + nq * 64;

  float4_t xr[4];
  float    wb[8];

  ISSUE_A(0); ISSUE_B(0); STORE_AB(0); BARRIER();
#pragma unroll 2
  for (int s = 0; s < 8; ++s) {
    const int cur = s & 1;
    if (s + 1 < 8) {
      ISSUE_A(s + 1); ISSUE_B(s + 1);
      STORE_AB(cur ^ 1);
      BARRIER();
    }
  }
  // keep-alive: read back staged LDS so nothing is dead
  float acc = (float)Al[0][tid >> 1][tid & 31] + (float)Al[1][128 - 1 - (tid >> 1)][tid & 31]
            + (float)Bl[0][b_n][(tid >> 3) & 31] + (float)Bl[1][b_n][(tid >> 4) & 31];
  sink[(((unsigned)blockIdx.x << 8) | tid) & 0xFFFFFu] = acc;
}

// ========== C: compute-structure ablation (loads -> L2-hot W region; sum-sink) ==========
__global__ __launch_bounds__(256, 4)
void siren_ablate_compute(const float* __restrict__ w,
                          const float* __restrict__ bias,
                          const void* __restrict__ idx_raw,
                          float* __restrict__ sink) {
  __shared__ __align__(16) _Float16 Al[2][128][LDKA];
  __shared__ __align__(16) _Float16 Bl[2][64][LDKB];
  SETUP_COMMON();
  (void)mh;

  // Same instruction mix as A, but "x" loads point at this tile's W block:
  // 256 KB, shared by 8 blocks -> pure L2 hits, ~zero HBM fetch.
  const float* __restrict__ Xg = w + (size_t)ch * 65536;
  const float* __restrict__ Wg = w + (size_t)ch * 65536 + nq * 64;

  float4_t acc[4][2];
#pragma unroll
  for (int m = 0; m < 4; ++m)
#pragma unroll
    for (int n = 0; n < 2; ++n)
      acc[m][n] = (float4_t){0.f, 0.f, 0.f, 0.f};

  float4_t xr[4];
  float    wb[8];

  ISSUE_A(0); ISSUE_B(0); STORE_AB(0); BARRIER();

  const int lane = tid & 63;
  const int wid  = tid >> 6;
  const int wm   = (wid >> 1) * 64;
  const int wn   = (wid & 1) * 32;
  const int fr   = lane & 15;
  const int kg   = lane >> 4;

#pragma unroll 2
  for (int s = 0; s < 8; ++s) {
    const int cur = s & 1;
    if (s + 1 < 8) { ISSUE_A(s + 1); ISSUE_B(s + 1); }

    half8_t af[4], bf[2];
#pragma unroll
    for (int m = 0; m < 4; ++m)
      af[m] = *(const half8_t*)&Al[cur][wm + m * 16 + fr][kg * 8];
#pragma unroll
    for (int n = 0; n < 2; ++n) {
      const int r = wn + n * 16 + fr;
      half4_t lo = *(const half4_t*)&Bl[cur][r][kg * 8];
      half4_t hi = *(const half4_t*)&Bl[cur][r][kg * 8 + 4];
      bf[n] = (half8_t){lo.x, lo.y, lo.z, lo.w, hi.x, hi.y, hi.z, hi.w};
    }

#pragma unroll
    for (int m = 0; m < 4; ++m)
#pragma unroll
      for (int n = 0; n < 2; ++n)
        acc[m][n] = __builtin_amdgcn_mfma_f32_16x16x32_f16(af[m], bf[n], acc[m][n], 0, 0, 0);

    if (s + 1 < 8) { STORE_AB(cur ^ 1); BARRIER(); }
  }

  // epilogue: keep sin VALU cost, sink via single store (no 268MB write stream)
  float bv[2];
#pragma unroll
  for (int n = 0; n < 2; ++n) bv[n] = OMEGA_C * bias[nq * 64 + wn + n * 16 + fr];

  float ssum = 0.f;
#pragma unroll
  for (int m = 0; m < 4; ++m)
#pragma unroll
    for (int n = 0; n < 2; ++n)
#pragma unroll
      for (int j = 0; j < 4; ++j)
        ssum += __sinf(fmaf(OMEGA_C, acc[m][n][j], bv[n]));
  sink[(((unsigned)blockIdx.x << 8) | tid) & 0xFFFFFu] = ssum;
}

extern "C" void kernel_launch(void* const* d_in, const int* in_sizes, int n_in,
                              void* d_out, int out_size, void* d_ws, size_t ws_size,
                              hipStream_t stream) {
  const float* x    = (const float*)d_in[0];
  const float* w    = (const float*)d_in[1];
  const float* bias = (const float*)d_in[2];
  const void*  idx  = d_in[3];
  float*       out  = (float*)d_out;

  // A: real kernel (d_out correctness)
  siren_tile_gemm<<<8192, 256, 0, stream>>>(x, w, bias, idx, out);

  // B, C: ablation probes into scratch (skipped if ws too small)
  if (ws_size >= (size_t)(1u << 22)) {
    float* sink = (float*)d_ws;
    siren_ablate_stage<<<8192, 256, 0, stream>>>(x, w, idx, sink);
    siren_ablate_compute<<<8192, 256, 0, stream>>>(w, bias, idx, sink);
  }
}

// Round 9
// 211.785 us; speedup vs baseline: 1.6848x; 1.6848x over previous
//
#include <hip/hip_runtime.h>

typedef _Float16 half8_t __attribute__((ext_vector_type(8)));
typedef _Float16 half4_t __attribute__((ext_vector_type(4)));
typedef float    float4_t __attribute__((ext_vector_type(4)));

#define OMEGA_C 30.0f

// lgkm-only barrier: LDS ops drain, global loads/stores stay in flight.
#define BARRIER() do {                                        \
    asm volatile("s_waitcnt lgkmcnt(0)" ::: "memory");        \
    __builtin_amdgcn_s_barrier();                             \
    asm volatile("" ::: "memory");                            \
  } while (0)

// One block = 64 rows x 256 cols (FULL output width).
//  - x read ONCE as contiguous 1KB rows (page-linear), f16 -> Xl (32KB, XOR-swz)
//  - A-fragments for ALL K hoisted to registers once, reused across 4 col-quarters
//  - W quarter [256k][64n] f16 -> Wl (32KB) per q, from L2/L3 (never HBM)
//  - K-loop is global-free; out rows complete page-grouped (4 q's back-to-back)
__global__ __launch_bounds__(256, 2)
void siren_fullk(const float* __restrict__ x,
                 const float* __restrict__ w,
                 const float* __restrict__ bias,
                 const void* __restrict__ idx_raw,
                 float* __restrict__ out) {
  __shared__ _Float16 Xl[64 * 256];   // 32 KB  [row][k]  granule-swizzled
  __shared__ _Float16 Wl[64 * 256];   // 32 KB  [col][k]  granule-swizzled

  const int tid  = threadIdx.x;
  const int lane = tid & 63;
  const int wvid = tid >> 6;          // wave 0..3

  // XCD-chunked: the 4 row-groups of a tile are consecutive on one XCD.
  const int b    = blockIdx.x;        // 0..4095
  const int u    = (b & 7) * 512 + (b >> 3);
  const int tile = u >> 2;
  const int rg   = u & 3;             // 64-row group

  // indices dtype self-detect (int64 per reference; int32 if demoted).
  const int hiw   = ((const int*)idx_raw)[2 * lane + 1];
  const bool is32 = __any(hiw != 0);
  const int ch = is32 ? ((const int*)idx_raw)[tile]
                      : (int)(((const long long*)idx_raw)[tile]);

  const float* __restrict__ Xg = x + (size_t)tile * 65536 + (size_t)rg * 64 * 256;
  const float* __restrict__ Wg = w + (size_t)ch * 65536;
  float*       __restrict__ Og = out + (size_t)tile * 65536 + (size_t)rg * 64 * 256;

  // ---- issue x: 16 full 1KB contiguous rows per wave (page-linear stream) ----
  float4_t xv[16];
#pragma unroll
  for (int i = 0; i < 16; ++i)
    xv[i] = *(const float4_t*)(Xg + (size_t)(wvid * 16 + i) * 256 + lane * 4);

  // ---- issue W quarter 0 (after x: x-waits leave W in flight) ----
  const int wl16 = lane >> 4;         // k-row group 0..3
  const int wc4  = lane & 15;         // col-quad
  float4_t wv[16];
#pragma unroll
  for (int h = 0; h < 4; ++h)
#pragma unroll
    for (int j = 0; j < 4; ++j)
      wv[h * 4 + j] = *(const float4_t*)(Wg + (size_t)(wvid * 64 + wl16 * 16 + h * 4 + j) * 256 + wc4 * 4);

  // ---- commit x to LDS: granule g=lane>>1, phys = g ^ ((row&7)<<1) ----
#pragma unroll
  for (int i = 0; i < 16; ++i) {
    const int r = wvid * 16 + i;
    half4_t hx = {(_Float16)xv[i].x, (_Float16)xv[i].y,
                  (_Float16)xv[i].z, (_Float16)xv[i].w};
    const int phys = (lane >> 1) ^ ((r & 7) << 1);
    *(half4_t*)&Xl[r * 256 + phys * 8 + (lane & 1) * 4] = hx;
  }
  BARRIER();

  const int fr = lane & 15, kg = lane >> 4;
  const int wm = (wvid >> 1) * 32;    // wave rows 0-31 / 32-63
  const int wn = (wvid & 1) * 32;     // wave cols within quarter

  // ---- hoist ALL A fragments (q-invariant): 16 x half8 = 64 VGPR ----
  half8_t af[8][2];
#pragma unroll
  for (int ks = 0; ks < 8; ++ks)
#pragma unroll
    for (int m = 0; m < 2; ++m) {
      const int r    = wm + m * 16 + fr;
      const int phys = (ks * 4 + kg) ^ ((r & 7) << 1);
      af[ks][m] = *(const half8_t*)&Xl[r * 256 + phys * 8];
    }

  float bvq[4][2];
#pragma unroll
  for (int q = 0; q < 4; ++q)
#pragma unroll
    for (int n = 0; n < 2; ++n)
      bvq[q][n] = OMEGA_C * bias[q * 64 + wn + n * 16 + fr];

#pragma unroll
  for (int q = 0; q < 4; ++q) {
    // ---- commit Wq: thread has 4 k-quads x 4 cols; k-contig half4 per col ----
#pragma unroll
    for (int h = 0; h < 4; ++h) {
      const int lg = wvid * 8 + wl16 * 2 + (h >> 1);   // logical k-granule
#pragma unroll
      for (int i = 0; i < 4; ++i) {
        const int c = wc4 * 4 + i;                     // local col 0..63
        half4_t hb = {(_Float16)wv[h * 4 + 0][i], (_Float16)wv[h * 4 + 1][i],
                      (_Float16)wv[h * 4 + 2][i], (_Float16)wv[h * 4 + 3][i]};
        const int phys = lg ^ ((c & 7) << 1);
        *(half4_t*)&Wl[c * 256 + phys * 8 + (h & 1) * 4] = hb;
      }
    }
    BARRIER();

    // issue W(q+1) while computing q (stays in flight through MFMA phase)
    if (q < 3) {
#pragma unroll
      for (int h = 0; h < 4; ++h)
#pragma unroll
        for (int j = 0; j < 4; ++j)
          wv[h * 4 + j] = *(const float4_t*)(Wg + (size_t)(wvid * 64 + wl16 * 16 + h * 4 + j) * 256 + (q + 1) * 64 + wc4 * 4);
    }

    float4_t acc[2][2];
#pragma unroll
    for (int m = 0; m < 2; ++m)
#pragma unroll
      for (int n = 0; n < 2; ++n)
        acc[m][n] = (float4_t){0.f, 0.f, 0.f, 0.f};

    // ---- K sweep entirely from LDS/registers ----
#pragma unroll
    for (int ks = 0; ks < 8; ++ks) {
      half8_t bf[2];
#pragma unroll
      for (int n = 0; n < 2; ++n) {
        const int c    = wn + n * 16 + fr;
        const int phys = (ks * 4 + kg) ^ ((c & 7) << 1);
        bf[n] = *(const half8_t*)&Wl[c * 256 + phys * 8];
      }
#pragma unroll
      for (int m = 0; m < 2; ++m)
#pragma unroll
        for (int n = 0; n < 2; ++n)
          acc[m][n] = __builtin_amdgcn_mfma_f32_16x16x32_f16(af[ks][m], bf[n], acc[m][n], 0, 0, 0);
    }
    BARRIER();   // Wl reads done; epilogue overlaps next q's ds_write

    // ---- epilogue q: 64x64 chunk final (C/D: col=lane&15, row=(lane>>4)*4+j) ----
#pragma unroll
    for (int m = 0; m < 2; ++m)
#pragma unroll
      for (int n = 0; n < 2; ++n)
#pragma unroll
        for (int j = 0; j < 4; ++j) {
          const int row = wm + m * 16 + kg * 4 + j;
          const int col = q * 64 + wn + n * 16 + fr;
          Og[(size_t)row * 256 + col] = __sinf(fmaf(OMEGA_C, acc[m][n][j], bvq[q][n]));
        }
  }
}

extern "C" void kernel_launch(void* const* d_in, const int* in_sizes, int n_in,
                              void* d_out, int out_size, void* d_ws, size_t ws_size,
                              hipStream_t stream) {
  const float* x    = (const float*)d_in[0];
  const float* w    = (const float*)d_in[1];
  const float* bias = (const float*)d_in[2];
  const void*  idx  = d_in[3];
  float*       out  = (float*)d_out;

  siren_fullk<<<4096, 256, 0, stream>>>(x, w, bias, idx, out);
}